// Round 22
// baseline (31.357 us; speedup 1.0000x reference)
//
#include <hip/hip_runtime.h>
#include <math.h>

#define KW_ELEMS 294912   // 3*3*128*256
#define KW_F4    73728    // KW_ELEMS/4
#define LR_GD 0.01
#define NBLK_RED 64       // stats partial blocks
#define NBLK_GC  256      // gram partial blocks
#define NBLK_XR  128      // XE rider blocks per host kernel

typedef __attribute__((ext_vector_type(8))) short short8;
typedef __attribute__((ext_vector_type(4))) float f32x4;

// ws layout (bytes):
//   0      : double stats_parts[64][2]                     1024 B
//   1024   : gram slots[256] {int n[5]; pad; double S[5]}  256*64 B
//   17408  : ushort W2[9][4][4][256][8]  (bf16)          589824 B
//   607232 : ushort XE[8][34][34][128]   (bf16, padded, pos-swizzled)
#define WS_SP_OFF    0
#define WS_GP_OFF    1024
#define WS_WP_OFF    17408
#define WS_XE_OFF    607232
#define XE_CHUNKS    (8 * 34 * 34 * 16)   // 147968 16B chunks
#define XE_HALF      (XE_CHUNKS / 2)      // 73984

__device__ __forceinline__ unsigned short f2bf(float f) {
    union { float f; unsigned int u; } v; v.f = f;
    unsigned int r = v.u + 0x7fffu + ((v.u >> 16) & 1u);   // RNE
    return (unsigned short)(r >> 16);
}

// lane-parallel read of the 128 stats partials + butterfly reduce.
__device__ __forceinline__ void read_stats(const double* sp, double& sw, double& sw2) {
    int lane = threadIdx.x & 63;
    double a = sp[2 * lane];
    double b = sp[2 * lane + 1];
    #pragma unroll
    for (int off = 32; off > 0; off >>= 1) {
        a += __shfl_xor(a, off, 64);
        b += __shfl_xor(b, off, 64);
    }
    sw = a; sw2 = b;
}

// sign(clip(x+s,0,1)-0.5) == sign((x+s)-0.5) exactly.
__device__ __forceinline__ float xeff_one(float xv, float s0, float s1, float s2,
                                          float be0, float be1, float be2) {
    float v0 = xv + s0, v1 = xv + s1, v2 = xv + s2;
    float g0 = (v0 > 0.5f) ? 1.0f : ((v0 < 0.5f) ? -1.0f : 0.0f);
    float g1 = (v1 > 0.5f) ? 1.0f : ((v1 < 0.5f) ? -1.0f : 0.0f);
    float g2 = (v2 > 0.5f) ? 1.0f : ((v2 < 0.5f) ? -1.0f : 0.0f);
    return be0 * g0 + be1 * g1 + be2 * g2;
}

// XE producer: chunks [c0, c1), grid-stride by nblk*256.
// XE[b][row 0..33][pos 0..33][128] bf16, borders zero, pos-keyed 16B XOR swizzle.
__device__ __forceinline__ void xe_produce(const float* __restrict__ x,
                                           const float* __restrict__ shiftp,
                                           const float* __restrict__ beta,
                                           char* __restrict__ wsv,
                                           int blk, int nblk, int c0, int c1) {
    unsigned short* xe = (unsigned short*)(wsv + WS_XE_OFF);
    float s0 = shiftp[0], s1v = shiftp[1], s2v = shiftp[2];
    float be0 = beta[0], be1 = beta[1], be2 = beta[2];
    int tid = threadIdx.x;

    for (int idx = c0 + blk * 256 + tid; idx < c1; idx += nblk * 256) {
        int cb  = idx & 15;
        int c2  = idx >> 4;            // (b*34+row)*34 + pos
        int pos = c2 % 34;
        int t   = c2 / 34;
        int row = t % 34;
        int b   = t / 34;
        int g   = row - 1;
        int wp  = pos - 1;
        unsigned short v[8] = {0, 0, 0, 0, 0, 0, 0, 0};
        if (g >= 0 && g < 32 && wp >= 0 && wp < 32) {
            const float* xp = &x[(((b * 32 + g) * 32) + wp) * 128 + cb * 8];
            float4 x0 = *(const float4*)(xp);
            float4 x1 = *(const float4*)(xp + 4);
            float e[8] = {x0.x, x0.y, x0.z, x0.w, x1.x, x1.y, x1.z, x1.w};
            #pragma unroll
            for (int j = 0; j < 8; j++)
                v[j] = f2bf(xeff_one(e[j], s0, s1v, s2v, be0, be1, be2));
        }
        int dst = c2 * 256 + ((cb * 16) ^ ((pos & 7) << 4));
        *(short8*)((char*)xe + dst) = *(short8*)v;
    }
}

// ---------------- K1: stats partials only (64 blocks, short) -----------------
__global__ __launch_bounds__(256) void k_pre(const float* __restrict__ w,
                                             void* __restrict__ wsv) {
    int tid = threadIdx.x;
    double* sp = (double*)((char*)wsv + WS_SP_OFF);
    __shared__ double s1[256];
    __shared__ double s2[256];

    double a = 0.0, b = 0.0;
    for (int i4 = blockIdx.x * 256 + tid; i4 < KW_F4; i4 += NBLK_RED * 256) {
        float4 v = *(const float4*)(&w[i4 * 4]);
        a += (double)v.x + (double)v.y + (double)v.z + (double)v.w;
        b += (double)v.x * (double)v.x + (double)v.y * (double)v.y
           + (double)v.z * (double)v.z + (double)v.w * (double)v.w;
    }
    s1[tid] = a; s2[tid] = b;
    __syncthreads();
    for (int off = 128; off > 0; off >>= 1) {
        if (tid < off) { s1[tid] += s1[tid + off]; s2[tid] += s2[tid + off]; }
        __syncthreads();
    }
    if (tid == 0) { sp[blockIdx.x * 2] = s1[0]; sp[blockIdx.x * 2 + 1] = s2[0]; }
}

// ---------------- K2: CDF gram partials (blocks 0-255) + XE riders (256-383) -
__global__ __launch_bounds__(256) void k_gc(const float* __restrict__ w,
                                            const float* __restrict__ x,
                                            const float* __restrict__ shiftp,
                                            const float* __restrict__ beta,
                                            void* __restrict__ wsv) {
    if (blockIdx.x >= NBLK_GC) {
        // XE riders: first half of chunks
        xe_produce(x, shiftp, beta, (char*)wsv,
                   blockIdx.x - NBLK_GC, NBLK_XR, 0, XE_HALF);
        return;
    }

    const double* sp = (const double*)((const char*)wsv + WS_SP_OFF);
    char* gp = (char*)wsv + WS_GP_OFF;

    __shared__ int    lg[4][5];
    __shared__ double lc[4][5];

    int tid  = threadIdx.x;
    int lane = tid & 63;
    int wave = tid >> 6;

    double sw, sw2;
    read_stats(sp, sw, sw2);
    double mean = sw / (double)KW_ELEMS;
    double var  = sw2 / (double)KW_ELEMS - mean * mean;
    float meanf = (float)mean;
    float sigf  = sqrtf((float)var);

    float thr[5];
    #pragma unroll
    for (int m = 0; m < 5; m++) thr[m] = (1.0f - 0.5f * (float)m) * sigf;

    int   cnt[5] = {0, 0, 0, 0, 0};
    float ss[5]  = {0.f, 0.f, 0.f, 0.f, 0.f};
    for (int i4 = blockIdx.x * 256 + tid; i4 < KW_F4; i4 += NBLK_GC * 256) {
        float4 v = *(const float4*)(&w[i4 * 4]);
        float e[4] = {v.x, v.y, v.z, v.w};
        #pragma unroll
        for (int j = 0; j < 4; j++) {
            float base = e[j] - meanf;
            #pragma unroll
            for (int m = 0; m < 5; m++) {
                bool bel = base < thr[m];
                cnt[m] += bel ? 1 : 0;
                ss[m]  += bel ? e[j] : 0.f;
            }
        }
    }
    double sd[5];
    #pragma unroll
    for (int m = 0; m < 5; m++) sd[m] = (double)ss[m];
    #pragma unroll
    for (int m = 0; m < 5; m++) {
        int c = cnt[m]; double s = sd[m];
        #pragma unroll
        for (int off = 32; off > 0; off >>= 1) {
            c += __shfl_xor(c, off, 64);
            s += __shfl_xor(s, off, 64);
        }
        cnt[m] = c; sd[m] = s;
    }
    if (lane == 0) {
        #pragma unroll
        for (int m = 0; m < 5; m++) { lg[wave][m] = cnt[m]; lc[wave][m] = sd[m]; }
    }
    __syncthreads();
    if (tid == 0) {
        int*    pn = (int*)(gp + blockIdx.x * 64);
        double* pS = (double*)(gp + blockIdx.x * 64 + 24);
        #pragma unroll
        for (int m = 0; m < 5; m++) {
            pn[m] = lg[0][m] + lg[1][m] + lg[2][m] + lg[3][m];
            pS[m] = lc[0][m] + lc[1][m] + lc[2][m] + lc[3][m];
        }
    }
}

// ---------------- K3: W2 pack + solve (blocks 0-143) + XE riders (144-271) ---
__global__ __launch_bounds__(256) void k_weff(const float* __restrict__ w,
                                              const float* __restrict__ a0f,
                                              const float* __restrict__ x,
                                              const float* __restrict__ shiftp,
                                              const float* __restrict__ beta,
                                              void* __restrict__ wsv) {
    if (blockIdx.x >= 144) {
        // XE riders: second half of chunks
        xe_produce(x, shiftp, beta, (char*)wsv,
                   blockIdx.x - 144, NBLK_XR, XE_HALF, XE_CHUNKS);
        return;
    }

    const double* sp = (const double*)((const char*)wsv + WS_SP_OFF);
    const char*   gp = (const char*)wsv + WS_GP_OFF;
    unsigned short* wpk = (unsigned short*)((char*)wsv + WS_WP_OFF);

    __shared__ double Gd[25];
    __shared__ double RmL[25];
    __shared__ double astar_s[5];
    __shared__ float  alph[5];
    __shared__ float  tile[32][64];

    int tid   = threadIdx.x;
    int lane  = tid & 63;
    int tap   = blockIdx.x >> 4;
    int rest  = blockIdx.x & 15;
    int c32   = rest >> 2;          // cin 32-block index
    int cin0  = c32 * 32;
    int cout0 = (rest & 3) * 64;

    // phase A: issue tile loads — in flight during solve
    int i0 = tid, i1 = tid + 256;
    int ci0 = i0 >> 4, f40 = i0 & 15;
    int ci1 = i1 >> 4, f41 = i1 & 15;
    float4 v0 = *(const float4*)(&w[(tap * 128 + cin0 + ci0) * 256 + cout0 + f40 * 4]);
    float4 v1 = *(const float4*)(&w[(tap * 128 + cin0 + ci1) * 256 + cout0 + f41 * 4]);

    double sw, sw2;
    read_stats(sp, sw, sw2);
    double mean = sw / (double)KW_ELEMS;
    double var  = sw2 / (double)KW_ELEMS - mean * mean;
    float meanf = (float)mean;
    float sigf  = sqrtf((float)var);

    // lane-parallel reduce of the 256 gram slots (lane l owns slots l+64q)
    int nred[5]; double Sred[5];
    #pragma unroll
    for (int m = 0; m < 5; m++) { nred[m] = 0; Sred[m] = 0.0; }
    #pragma unroll
    for (int q = 0; q < 4; q++) {
        const int*    pn = (const int*)(gp + (lane + q * 64) * 64);
        const double* pS = (const double*)(gp + (lane + q * 64) * 64 + 24);
        #pragma unroll
        for (int m = 0; m < 5; m++) { nred[m] += pn[m]; Sred[m] += pS[m]; }
    }
    #pragma unroll
    for (int m = 0; m < 5; m++) {
        int c = nred[m]; double s = Sred[m];
        #pragma unroll
        for (int off = 32; off > 0; off >>= 1) {
            c += __shfl_xor(c, off, 64);
            s += __shfl_xor(s, off, 64);
        }
        nred[m] = c; Sred[m] = s;
    }
    double Creg[5];
    #pragma unroll
    for (int m = 0; m < 5; m++)
        Creg[m] = (sw - 2.0 * Sred[m]) / (double)KW_ELEMS;

    // G in registers of wave-0 lanes 0-24 (CDF identity), publish Gd for wave 1
    double Rg = 0.0, Ag = 0.0;
    {
        int i = tid / 5, j = tid % 5;
        if (tid < 25) {
            double v;
            if (i == j) v = 1.0;
            else {
                int d = nred[i] - nred[j];
                if (d < 0) d = -d;
                v = ((double)KW_ELEMS - 2.0 * (double)d) / (double)KW_ELEMS;
            }
            Gd[tid] = v;
            Ag = ((i == j) ? 1.0 : 0.0) - LR_GD * v;
            Rg = Ag;
        }
    }
    __syncthreads();   // Gd visible to wave 1

    // wave 1, lane 64: Cholesky + triangular solves, concurrent with rounds.
    if (tid == 64) {
        double L[25];
        #pragma unroll
        for (int i = 0; i < 25; i++) L[i] = 0.0;
        #pragma unroll
        for (int i = 0; i < 5; i++) {
            #pragma unroll
            for (int j = 0; j <= i; j++) {
                double s = Gd[i * 5 + j];
                #pragma unroll
                for (int k = 0; k < j; k++) s -= L[i * 5 + k] * L[j * 5 + k];
                if (i == j) L[i * 5 + j] = sqrt(s);
                else        L[i * 5 + j] = s / L[j * 5 + j];
            }
        }
        double y[5], astar[5];
        #pragma unroll
        for (int i = 0; i < 5; i++) {
            double s = Creg[i];
            #pragma unroll
            for (int k = 0; k < i; k++) s -= L[i * 5 + k] * y[k];
            y[i] = s / L[i * 5 + i];
        }
        #pragma unroll
        for (int ii2 = 0; ii2 < 5; ii2++) {
            int i = 4 - ii2;
            double s = y[i];
            #pragma unroll
            for (int k = 0; k < 5; k++) if (k > i) s -= L[k * 5 + i] * astar[k];
            astar[i] = s / L[i * 5 + i];
        }
        #pragma unroll
        for (int i = 0; i < 5; i++) astar_s[i] = astar[i];
    }

    // A^500 via in-wave shuffles (wave 0, lanes 0-24 all active in branch).
    // 500 bits: 1,1,1,1,0,1,0,0. Final R spilled to LDS for the epilogue.
    if (tid < 25) {
        int i = tid / 5, j = tid % 5;
        const int bits[8] = {1, 1, 1, 1, 0, 1, 0, 0};
        #pragma unroll
        for (int s = 0; s < 8; s++) {
            double t = 0.0;
            #pragma unroll
            for (int k = 0; k < 5; k++) {
                double rik = __shfl(Rg, i * 5 + k, 64);
                double rkj = __shfl(Rg, k * 5 + j, 64);
                t += rik * rkj;
            }
            if (bits[s]) {
                double r2 = 0.0;
                #pragma unroll
                for (int k = 0; k < 5; k++) {
                    double tik = __shfl(t, i * 5 + k, 64);
                    double akj = __shfl(Ag, k * 5 + j, 64);
                    r2 += tik * akj;
                }
                Rg = r2;
            } else {
                Rg = t;
            }
        }
        RmL[tid] = Rg;
    }
    __syncthreads();   // RmL + astar_s ready

    // alph = astar + R (a0 - astar), lanes 0-4 read R from LDS
    if (tid < 5) {
        double s = astar_s[tid];
        #pragma unroll
        for (int j = 0; j < 5; j++)
            s += RmL[tid * 5 + j] * ((double)a0f[j] - astar_s[j]);
        alph[tid] = (float)s;
    }
    __syncthreads();

    float al[5] = {alph[0], alph[1], alph[2], alph[3], alph[4]};

    // phase C: combine + LDS transpose + bf16 pack
    {
        float r[4] = {v0.x, v0.y, v0.z, v0.w};
        #pragma unroll
        for (int j = 0; j < 4; j++) {
            float base = r[j] - meanf;
            float acc = 0.0f;
            #pragma unroll
            for (int m = 0; m < 5; m++) {
                float arg = base + (-1.0f + 0.5f * (float)m) * sigf;
                float s = (arg > 0.0f) ? 1.0f : ((arg < 0.0f) ? -1.0f : 0.0f);
                acc += al[m] * s;
            }
            tile[ci0][f40 * 4 + j] = acc;
        }
        float r1[4] = {v1.x, v1.y, v1.z, v1.w};
        #pragma unroll
        for (int j = 0; j < 4; j++) {
            float base = r1[j] - meanf;
            float acc = 0.0f;
            #pragma unroll
            for (int m = 0; m < 5; m++) {
                float arg = base + (-1.0f + 0.5f * (float)m) * sigf;
                float s = (arg > 0.0f) ? 1.0f : ((arg < 0.0f) ? -1.0f : 0.0f);
                acc += al[m] * s;
            }
            tile[ci1][f41 * 4 + j] = acc;
        }
    }
    __syncthreads();

    int cc  = tid & 63;
    int kg  = tid >> 6;          // 8-cin chunk within the 32-block
    unsigned short ob[8];
    #pragma unroll
    for (int k = 0; k < 8; k++) ob[k] = f2bf(tile[kg * 8 + k][cc]);
    unsigned short* dst = wpk + (((tap * 16 + c32 * 4 + kg) * 256) + cout0 + cc) * 8;
    *(short8*)dst = *(short8*)ob;
}

// ---------------- K4: conv via bf16 MFMA, pure-copy staging ------------------
// grid 512 = b(8) x h(32) x cout-half(2); 256 thr = 4 waves.
__global__ __launch_bounds__(256, 2) void k_conv(
    const void* __restrict__ wsv, float* __restrict__ out) {
    const unsigned short* wp = (const unsigned short*)((const char*)wsv + WS_WP_OFF);
    const char* xe = (const char*)wsv + WS_XE_OFF;
    __shared__ __align__(16) unsigned short ldsx[3 * 34 * 128];   // 26112 B

    int bid = blockIdx.x;
    int ch  = bid & 1;
    int h   = (bid >> 1) & 31;
    int b   = bid >> 6;
    int tid = threadIdx.x;

    // staging: padded rows h..h+2 = contiguous 26112 B, pre-swizzled.
    const char* src = xe + ((b * 34 + h) * 34) * 256;
    #pragma unroll 2
    for (int i = tid; i < 1632; i += 256) {
        *(short8*)((char*)ldsx + i * 16) = *(const short8*)(src + i * 16);
    }
    __syncthreads();

    int lane = tid & 63;
    int wave = tid >> 6;
    int l15  = lane & 15;
    int kg   = lane >> 4;
    int coutbase = (ch << 7) + wave * 32;

    f32x4 acc[2][2];
    #pragma unroll
    for (int mt = 0; mt < 2; mt++)
        #pragma unroll
        for (int nt = 0; nt < 2; nt++) acc[mt][nt] = (f32x4){0.f, 0.f, 0.f, 0.f};

    // per-lane weight base; tap stride = 32768 ushorts, q stride = 8192,
    // nt stride = 128.
    const unsigned short* wbase = wp + ((kg * 256) + coutbase + l15) * 8;

    short8 bc[8], bn[8];
    #pragma unroll
    for (int q = 0; q < 4; q++) {
        bc[2 * q]     = *(const short8*)(wbase + q * 8192);
        bc[2 * q + 1] = *(const short8*)(wbase + q * 8192 + 128);
    }

    #pragma unroll
    for (int dh = 0; dh < 3; dh++) {
        #pragma unroll
        for (int dw = 0; dw < 3; dw++) {
            int tap = dh * 3 + dw;
            if (tap < 8) {
                const unsigned short* wnx = wbase + (tap + 1) * 32768;
                #pragma unroll
                for (int q = 0; q < 4; q++) {
                    bn[2 * q]     = *(const short8*)(wnx + q * 8192);
                    bn[2 * q + 1] = *(const short8*)(wnx + q * 8192 + 128);
                }
            }
            int r0  = dh * 34 + l15 + dw;        // LDS row (pos part = l15+dw)
            int r1  = r0 + 16;                   // +16: same key mod 8
            int key = ((l15 + dw) & 7) << 4;     // pos-keyed swizzle
            #pragma unroll
            for (int q = 0; q < 4; q++) {
                int cbyte = q * 64 + kg * 16;
                short8 a0f8 = *(const short8*)((const char*)ldsx +
                               (r0 * 256 + (cbyte ^ key)));
                short8 a1f8 = *(const short8*)((const char*)ldsx +
                               (r1 * 256 + (cbyte ^ key)));
                acc[0][0] = __builtin_amdgcn_mfma_f32_16x16x32_bf16(a0f8, bc[2*q],   acc[0][0], 0, 0, 0);
                acc[0][1] = __builtin_amdgcn_mfma_f32_16x16x32_bf16(a0f8, bc[2*q+1], acc[0][1], 0, 0, 0);
                acc[1][0] = __builtin_amdgcn_mfma_f32_16x16x32_bf16(a1f8, bc[2*q],   acc[1][0], 0, 0, 0);
                acc[1][1] = __builtin_amdgcn_mfma_f32_16x16x32_bf16(a1f8, bc[2*q+1], acc[1][1], 0, 0, 0);
            }
            if (tap < 8) {
                #pragma unroll
                for (int i = 0; i < 8; i++) bc[i] = bn[i];
            }
        }
    }

    // D: col = lane&15 (cout), row = kg*4 + reg (pos within 16-tile)
    #pragma unroll
    for (int mt = 0; mt < 2; mt++) {
        #pragma unroll
        for (int nt = 0; nt < 2; nt++) {
            int col = coutbase + nt * 16 + l15;
            #pragma unroll
            for (int reg = 0; reg < 4; reg++) {
                int row = mt * 16 + kg * 4 + reg;
                out[(((b * 32 + h) * 32) + row) * 256 + col] = acc[mt][nt][reg];
            }
        }
    }
}

extern "C" void kernel_launch(void* const* d_in, const int* in_sizes, int n_in,
                              void* d_out, int out_size, void* d_ws, size_t ws_size,
                              hipStream_t stream) {
    const float* x      = (const float*)d_in[0];
    const float* w      = (const float*)d_in[1];
    const float* shiftp = (const float*)d_in[2];
    const float* beta   = (const float*)d_in[3];
    const float* a0     = (const float*)d_in[4];
    float* out = (float*)d_out;

    k_pre<<<NBLK_RED, 256, 0, stream>>>(w, d_ws);
    k_gc<<<NBLK_GC + NBLK_XR, 256, 0, stream>>>(w, x, shiftp, beta, d_ws);
    k_weff<<<144 + NBLK_XR, 256, 0, stream>>>(w, a0, x, shiftp, beta, d_ws);
    k_conv<<<512, 256, 0, stream>>>(d_ws, out);
}

// Round 23
// 30.471 us; speedup vs baseline: 1.0291x; 1.0291x over previous
//
#include <hip/hip_runtime.h>
#include <math.h>

#define KW_ELEMS 294912   // 3*3*128*256
#define KW_F4    73728    // KW_ELEMS/4
#define LR_GD 0.01
#define NBLK_RED 64       // stats partial blocks
#define NBLK_XE  192      // XE blocks (k_pre grid = 64+192)
#define NBLK_GC  256      // gram partial blocks

typedef __attribute__((ext_vector_type(8))) short short8;
typedef __attribute__((ext_vector_type(4))) float f32x4;

// ws layout (bytes):
//   0      : double stats_parts[64][2]                     1024 B
//   1024   : gram slots[256] {int n[5]; pad; double S[5]}  256*64 B
//   17408  : ushort W2[9][4][4][256][8]  (bf16)          589824 B
//   607232 : ushort XE[8][34][34][128]   (bf16, padded, pos-swizzled)
#define WS_SP_OFF    0
#define WS_GP_OFF    1024
#define WS_WP_OFF    17408
#define WS_XE_OFF    607232
#define XE_CHUNKS    (8 * 34 * 34 * 16)   // 16B chunks

__device__ __forceinline__ unsigned short f2bf(float f) {
    union { float f; unsigned int u; } v; v.f = f;
    unsigned int r = v.u + 0x7fffu + ((v.u >> 16) & 1u);   // RNE
    return (unsigned short)(r >> 16);
}

// lane-parallel read of the 128 stats partials + butterfly reduce.
__device__ __forceinline__ void read_stats(const double* sp, double& sw, double& sw2) {
    int lane = threadIdx.x & 63;
    double a = sp[2 * lane];
    double b = sp[2 * lane + 1];
    #pragma unroll
    for (int off = 32; off > 0; off >>= 1) {
        a += __shfl_xor(a, off, 64);
        b += __shfl_xor(b, off, 64);
    }
    sw = a; sw2 = b;
}

// sign(clip(x+s,0,1)-0.5) == sign((x+s)-0.5) exactly.
__device__ __forceinline__ float xeff_one(float xv, float s0, float s1, float s2,
                                          float be0, float be1, float be2) {
    float v0 = xv + s0, v1 = xv + s1, v2 = xv + s2;
    float g0 = (v0 > 0.5f) ? 1.0f : ((v0 < 0.5f) ? -1.0f : 0.0f);
    float g1 = (v1 > 0.5f) ? 1.0f : ((v1 < 0.5f) ? -1.0f : 0.0f);
    float g2 = (v2 > 0.5f) ? 1.0f : ((v2 < 0.5f) ? -1.0f : 0.0f);
    return be0 * g0 + be1 * g1 + be2 * g2;
}

// ---------------- K1: stats partials (blocks 0-63) + X_eff buffer (64-255) ---
__global__ __launch_bounds__(256) void k_pre(const float* __restrict__ w,
                                             const float* __restrict__ x,
                                             const float* __restrict__ shiftp,
                                             const float* __restrict__ beta,
                                             void* __restrict__ wsv) {
    int tid = threadIdx.x;

    if (blockIdx.x < NBLK_RED) {
        double* sp = (double*)((char*)wsv + WS_SP_OFF);
        __shared__ double s1[256];
        __shared__ double s2[256];

        double a = 0.0, b = 0.0;
        for (int i4 = blockIdx.x * 256 + tid; i4 < KW_F4; i4 += NBLK_RED * 256) {
            float4 v = *(const float4*)(&w[i4 * 4]);
            a += (double)v.x + (double)v.y + (double)v.z + (double)v.w;
            b += (double)v.x * (double)v.x + (double)v.y * (double)v.y
               + (double)v.z * (double)v.z + (double)v.w * (double)v.w;
        }
        s1[tid] = a; s2[tid] = b;
        __syncthreads();
        for (int off = 128; off > 0; off >>= 1) {
            if (tid < off) { s1[tid] += s1[tid + off]; s2[tid] += s2[tid + off]; }
            __syncthreads();
        }
        if (tid == 0) { sp[blockIdx.x * 2] = s1[0]; sp[blockIdx.x * 2 + 1] = s2[0]; }
    } else {
        // X_eff padded buffer: [b][row 0..33][pos 0..33][128] bf16,
        // borders zero, pos-keyed 16B XOR swizzle.
        unsigned short* xe = (unsigned short*)((char*)wsv + WS_XE_OFF);
        float s0 = shiftp[0], s1v = shiftp[1], s2v = shiftp[2];
        float be0 = beta[0], be1 = beta[1], be2 = beta[2];

        for (int idx = (blockIdx.x - NBLK_RED) * 256 + tid; idx < XE_CHUNKS;
             idx += NBLK_XE * 256) {
            int cb  = idx & 15;
            int c2  = idx >> 4;            // (b*34+row)*34 + pos
            int pos = c2 % 34;
            int t   = c2 / 34;
            int row = t % 34;
            int b   = t / 34;
            int g   = row - 1;
            int wp  = pos - 1;
            unsigned short v[8] = {0, 0, 0, 0, 0, 0, 0, 0};
            if (g >= 0 && g < 32 && wp >= 0 && wp < 32) {
                const float* xp = &x[(((b * 32 + g) * 32) + wp) * 128 + cb * 8];
                float4 x0 = *(const float4*)(xp);
                float4 x1 = *(const float4*)(xp + 4);
                float e[8] = {x0.x, x0.y, x0.z, x0.w, x1.x, x1.y, x1.z, x1.w};
                #pragma unroll
                for (int j = 0; j < 8; j++)
                    v[j] = f2bf(xeff_one(e[j], s0, s1v, s2v, be0, be1, be2));
            }
            int dst = c2 * 256 + ((cb * 16) ^ ((pos & 7) << 4));
            *(short8*)((char*)xe + dst) = *(short8*)v;
        }
    }
}

// ---------------- K2: CDF gram partials, 256 blocks, plain slot writes -------
__global__ __launch_bounds__(256) void k_gc(const float* __restrict__ w,
                                            void* __restrict__ wsv) {
    const double* sp = (const double*)((const char*)wsv + WS_SP_OFF);
    char* gp = (char*)wsv + WS_GP_OFF;

    __shared__ int    lg[4][5];
    __shared__ double lc[4][5];

    int tid  = threadIdx.x;
    int lane = tid & 63;
    int wave = tid >> 6;

    double sw, sw2;
    read_stats(sp, sw, sw2);
    double mean = sw / (double)KW_ELEMS;
    double var  = sw2 / (double)KW_ELEMS - mean * mean;
    float meanf = (float)mean;
    float sigf  = sqrtf((float)var);

    float thr[5];
    #pragma unroll
    for (int m = 0; m < 5; m++) thr[m] = (1.0f - 0.5f * (float)m) * sigf;

    int   cnt[5] = {0, 0, 0, 0, 0};
    float ss[5]  = {0.f, 0.f, 0.f, 0.f, 0.f};
    for (int i4 = blockIdx.x * 256 + tid; i4 < KW_F4; i4 += NBLK_GC * 256) {
        float4 v = *(const float4*)(&w[i4 * 4]);
        float e[4] = {v.x, v.y, v.z, v.w};
        #pragma unroll
        for (int j = 0; j < 4; j++) {
            float base = e[j] - meanf;
            #pragma unroll
            for (int m = 0; m < 5; m++) {
                bool bel = base < thr[m];
                cnt[m] += bel ? 1 : 0;
                ss[m]  += bel ? e[j] : 0.f;
            }
        }
    }
    double sd[5];
    #pragma unroll
    for (int m = 0; m < 5; m++) sd[m] = (double)ss[m];
    #pragma unroll
    for (int m = 0; m < 5; m++) {
        int c = cnt[m]; double s = sd[m];
        #pragma unroll
        for (int off = 32; off > 0; off >>= 1) {
            c += __shfl_xor(c, off, 64);
            s += __shfl_xor(s, off, 64);
        }
        cnt[m] = c; sd[m] = s;
    }
    if (lane == 0) {
        #pragma unroll
        for (int m = 0; m < 5; m++) { lg[wave][m] = cnt[m]; lc[wave][m] = sd[m]; }
    }
    __syncthreads();
    if (tid == 0) {
        int*    pn = (int*)(gp + blockIdx.x * 64);
        double* pS = (double*)(gp + blockIdx.x * 64 + 24);
        #pragma unroll
        for (int m = 0; m < 5; m++) {
            pn[m] = lg[0][m] + lg[1][m] + lg[2][m] + lg[3][m];
            pS[m] = lc[0][m] + lc[1][m] + lc[2][m] + lc[3][m];
        }
    }
}

// ---------------- K3: W2 pack + shuffle-based closed-form alpha solve --------
// grid 144 = tap(9) x cin-quarter(4) x cout-quarter(4).
__global__ __launch_bounds__(256) void k_weff(const float* __restrict__ w,
                                              const float* __restrict__ a0f,
                                              void* __restrict__ wsv) {
    const double* sp = (const double*)((const char*)wsv + WS_SP_OFF);
    const char*   gp = (const char*)wsv + WS_GP_OFF;
    unsigned short* wpk = (unsigned short*)((char*)wsv + WS_WP_OFF);

    __shared__ double Gd[25];
    __shared__ double RmL[25];
    __shared__ double astar_s[5];
    __shared__ float  alph[5];
    __shared__ float  tile[32][64];

    int tid   = threadIdx.x;
    int lane  = tid & 63;
    int tap   = blockIdx.x >> 4;
    int rest  = blockIdx.x & 15;
    int c32   = rest >> 2;          // cin 32-block index
    int cin0  = c32 * 32;
    int cout0 = (rest & 3) * 64;

    // phase A: issue tile loads — in flight during solve
    int i0 = tid, i1 = tid + 256;
    int ci0 = i0 >> 4, f40 = i0 & 15;
    int ci1 = i1 >> 4, f41 = i1 & 15;
    float4 v0 = *(const float4*)(&w[(tap * 128 + cin0 + ci0) * 256 + cout0 + f40 * 4]);
    float4 v1 = *(const float4*)(&w[(tap * 128 + cin0 + ci1) * 256 + cout0 + f41 * 4]);

    double sw, sw2;
    read_stats(sp, sw, sw2);
    double mean = sw / (double)KW_ELEMS;
    double var  = sw2 / (double)KW_ELEMS - mean * mean;
    float meanf = (float)mean;
    float sigf  = sqrtf((float)var);

    // lane-parallel reduce of the 256 gram slots (lane l owns slots l+64q)
    int nred[5]; double Sred[5];
    #pragma unroll
    for (int m = 0; m < 5; m++) { nred[m] = 0; Sred[m] = 0.0; }
    #pragma unroll
    for (int q = 0; q < 4; q++) {
        const int*    pn = (const int*)(gp + (lane + q * 64) * 64);
        const double* pS = (const double*)(gp + (lane + q * 64) * 64 + 24);
        #pragma unroll
        for (int m = 0; m < 5; m++) { nred[m] += pn[m]; Sred[m] += pS[m]; }
    }
    #pragma unroll
    for (int m = 0; m < 5; m++) {
        int c = nred[m]; double s = Sred[m];
        #pragma unroll
        for (int off = 32; off > 0; off >>= 1) {
            c += __shfl_xor(c, off, 64);
            s += __shfl_xor(s, off, 64);
        }
        nred[m] = c; Sred[m] = s;
    }
    double Creg[5];
    #pragma unroll
    for (int m = 0; m < 5; m++)
        Creg[m] = (sw - 2.0 * Sred[m]) / (double)KW_ELEMS;

    // G in registers of wave-0 lanes 0-24 (CDF identity), publish Gd for wave 1
    double Rg = 0.0, Ag = 0.0;
    {
        int i = tid / 5, j = tid % 5;
        if (tid < 25) {
            double v;
            if (i == j) v = 1.0;
            else {
                int d = nred[i] - nred[j];
                if (d < 0) d = -d;
                v = ((double)KW_ELEMS - 2.0 * (double)d) / (double)KW_ELEMS;
            }
            Gd[tid] = v;
            Ag = ((i == j) ? 1.0 : 0.0) - LR_GD * v;
            Rg = Ag;
        }
    }
    __syncthreads();   // Gd visible to wave 1

    // wave 1, lane 64: Cholesky + triangular solves, concurrent with rounds.
    if (tid == 64) {
        double L[25];
        #pragma unroll
        for (int i = 0; i < 25; i++) L[i] = 0.0;
        #pragma unroll
        for (int i = 0; i < 5; i++) {
            #pragma unroll
            for (int j = 0; j <= i; j++) {
                double s = Gd[i * 5 + j];
                #pragma unroll
                for (int k = 0; k < j; k++) s -= L[i * 5 + k] * L[j * 5 + k];
                if (i == j) L[i * 5 + j] = sqrt(s);
                else        L[i * 5 + j] = s / L[j * 5 + j];
            }
        }
        double y[5], astar[5];
        #pragma unroll
        for (int i = 0; i < 5; i++) {
            double s = Creg[i];
            #pragma unroll
            for (int k = 0; k < i; k++) s -= L[i * 5 + k] * y[k];
            y[i] = s / L[i * 5 + i];
        }
        #pragma unroll
        for (int ii2 = 0; ii2 < 5; ii2++) {
            int i = 4 - ii2;
            double s = y[i];
            #pragma unroll
            for (int k = 0; k < 5; k++) if (k > i) s -= L[k * 5 + i] * astar[k];
            astar[i] = s / L[i * 5 + i];
        }
        #pragma unroll
        for (int i = 0; i < 5; i++) astar_s[i] = astar[i];
    }

    // A^500 via in-wave shuffles (wave 0, lanes 0-24; ALL shuffle sources are
    // lanes <25, which are ACTIVE inside this branch). 500 bits: 1,1,1,1,0,1,0,0
    // Final R spilled to LDS (RmL) so the 5-lane epilogue never shuffles from
    // an inactive lane.
    if (tid < 25) {
        int i = tid / 5, j = tid % 5;
        const int bits[8] = {1, 1, 1, 1, 0, 1, 0, 0};
        #pragma unroll
        for (int s = 0; s < 8; s++) {
            double t = 0.0;
            #pragma unroll
            for (int k = 0; k < 5; k++) {
                double rik = __shfl(Rg, i * 5 + k, 64);
                double rkj = __shfl(Rg, k * 5 + j, 64);
                t += rik * rkj;
            }
            if (bits[s]) {
                double r2 = 0.0;
                #pragma unroll
                for (int k = 0; k < 5; k++) {
                    double tik = __shfl(t, i * 5 + k, 64);
                    double akj = __shfl(Ag, k * 5 + j, 64);
                    r2 += tik * akj;
                }
                Rg = r2;
            } else {
                Rg = t;
            }
        }
        RmL[tid] = Rg;
    }
    __syncthreads();   // RmL + astar_s ready

    // alph = astar + R (a0 - astar), lanes 0-4 read R from LDS
    if (tid < 5) {
        double s = astar_s[tid];
        #pragma unroll
        for (int j = 0; j < 5; j++)
            s += RmL[tid * 5 + j] * ((double)a0f[j] - astar_s[j]);
        alph[tid] = (float)s;
    }
    __syncthreads();

    float al[5] = {alph[0], alph[1], alph[2], alph[3], alph[4]};

    // phase C: combine + LDS transpose + bf16 pack
    {
        float r[4] = {v0.x, v0.y, v0.z, v0.w};
        #pragma unroll
        for (int j = 0; j < 4; j++) {
            float base = r[j] - meanf;
            float acc = 0.0f;
            #pragma unroll
            for (int m = 0; m < 5; m++) {
                float arg = base + (-1.0f + 0.5f * (float)m) * sigf;
                float s = (arg > 0.0f) ? 1.0f : ((arg < 0.0f) ? -1.0f : 0.0f);
                acc += al[m] * s;
            }
            tile[ci0][f40 * 4 + j] = acc;
        }
        float r1[4] = {v1.x, v1.y, v1.z, v1.w};
        #pragma unroll
        for (int j = 0; j < 4; j++) {
            float base = r1[j] - meanf;
            float acc = 0.0f;
            #pragma unroll
            for (int m = 0; m < 5; m++) {
                float arg = base + (-1.0f + 0.5f * (float)m) * sigf;
                float s = (arg > 0.0f) ? 1.0f : ((arg < 0.0f) ? -1.0f : 0.0f);
                acc += al[m] * s;
            }
            tile[ci1][f41 * 4 + j] = acc;
        }
    }
    __syncthreads();

    int cc  = tid & 63;
    int kg  = tid >> 6;          // 8-cin chunk within the 32-block
    unsigned short ob[8];
    #pragma unroll
    for (int k = 0; k < 8; k++) ob[k] = f2bf(tile[kg * 8 + k][cc]);
    unsigned short* dst = wpk + (((tap * 16 + c32 * 4 + kg) * 256) + cout0 + cc) * 8;
    *(short8*)dst = *(short8*)ob;
}

// ---------------- K4: conv via bf16 MFMA, pure-copy staging ------------------
// grid 512 = b(8) x h(32) x cout-half(2); 256 thr = 4 waves.
__global__ __launch_bounds__(256, 2) void k_conv(
    const void* __restrict__ wsv, float* __restrict__ out) {
    const unsigned short* wp = (const unsigned short*)((const char*)wsv + WS_WP_OFF);
    const char* xe = (const char*)wsv + WS_XE_OFF;
    __shared__ __align__(16) unsigned short ldsx[3 * 34 * 128];   // 26112 B

    int bid = blockIdx.x;
    int ch  = bid & 1;
    int h   = (bid >> 1) & 31;
    int b   = bid >> 6;
    int tid = threadIdx.x;

    // staging: padded rows h..h+2 = contiguous 26112 B, pre-swizzled.
    const char* src = xe + ((b * 34 + h) * 34) * 256;
    #pragma unroll 2
    for (int i = tid; i < 1632; i += 256) {
        *(short8*)((char*)ldsx + i * 16) = *(const short8*)(src + i * 16);
    }
    __syncthreads();

    int lane = tid & 63;
    int wave = tid >> 6;
    int l15  = lane & 15;
    int kg   = lane >> 4;
    int coutbase = (ch << 7) + wave * 32;

    f32x4 acc[2][2];
    #pragma unroll
    for (int mt = 0; mt < 2; mt++)
        #pragma unroll
        for (int nt = 0; nt < 2; nt++) acc[mt][nt] = (f32x4){0.f, 0.f, 0.f, 0.f};

    // per-lane weight base; tap stride = 32768 ushorts, q stride = 8192,
    // nt stride = 128.
    const unsigned short* wbase = wp + ((kg * 256) + coutbase + l15) * 8;

    short8 bc[8], bn[8];
    #pragma unroll
    for (int q = 0; q < 4; q++) {
        bc[2 * q]     = *(const short8*)(wbase + q * 8192);
        bc[2 * q + 1] = *(const short8*)(wbase + q * 8192 + 128);
    }

    #pragma unroll
    for (int dh = 0; dh < 3; dh++) {
        #pragma unroll
        for (int dw = 0; dw < 3; dw++) {
            int tap = dh * 3 + dw;
            if (tap < 8) {
                const unsigned short* wnx = wbase + (tap + 1) * 32768;
                #pragma unroll
                for (int q = 0; q < 4; q++) {
                    bn[2 * q]     = *(const short8*)(wnx + q * 8192);
                    bn[2 * q + 1] = *(const short8*)(wnx + q * 8192 + 128);
                }
            }
            int r0  = dh * 34 + l15 + dw;        // LDS row (pos part = l15+dw)
            int r1  = r0 + 16;                   // +16: same key mod 8
            int key = ((l15 + dw) & 7) << 4;     // pos-keyed swizzle
            #pragma unroll
            for (int q = 0; q < 4; q++) {
                int cbyte = q * 64 + kg * 16;
                short8 a0f8 = *(const short8*)((const char*)ldsx +
                               (r0 * 256 + (cbyte ^ key)));
                short8 a1f8 = *(const short8*)((const char*)ldsx +
                               (r1 * 256 + (cbyte ^ key)));
                acc[0][0] = __builtin_amdgcn_mfma_f32_16x16x32_bf16(a0f8, bc[2*q],   acc[0][0], 0, 0, 0);
                acc[0][1] = __builtin_amdgcn_mfma_f32_16x16x32_bf16(a0f8, bc[2*q+1], acc[0][1], 0, 0, 0);
                acc[1][0] = __builtin_amdgcn_mfma_f32_16x16x32_bf16(a1f8, bc[2*q],   acc[1][0], 0, 0, 0);
                acc[1][1] = __builtin_amdgcn_mfma_f32_16x16x32_bf16(a1f8, bc[2*q+1], acc[1][1], 0, 0, 0);
            }
            if (tap < 8) {
                #pragma unroll
                for (int i = 0; i < 8; i++) bc[i] = bn[i];
            }
        }
    }

    // D: col = lane&15 (cout), row = kg*4 + reg (pos within 16-tile)
    #pragma unroll
    for (int mt = 0; mt < 2; mt++) {
        #pragma unroll
        for (int nt = 0; nt < 2; nt++) {
            int col = coutbase + nt * 16 + l15;
            #pragma unroll
            for (int reg = 0; reg < 4; reg++) {
                int row = mt * 16 + kg * 4 + reg;
                out[(((b * 32 + h) * 32) + row) * 256 + col] = acc[mt][nt][reg];
            }
        }
    }
}

extern "C" void kernel_launch(void* const* d_in, const int* in_sizes, int n_in,
                              void* d_out, int out_size, void* d_ws, size_t ws_size,
                              hipStream_t stream) {
    const float* x      = (const float*)d_in[0];
    const float* w      = (const float*)d_in[1];
    const float* shiftp = (const float*)d_in[2];
    const float* beta   = (const float*)d_in[3];
    const float* a0     = (const float*)d_in[4];
    float* out = (float*)d_out;

    k_pre<<<NBLK_RED + NBLK_XE, 256, 0, stream>>>(w, x, shiftp, beta, d_ws);
    k_gc<<<NBLK_GC, 256, 0, stream>>>(w, d_ws);
    k_weff<<<144, 256, 0, stream>>>(w, a0, d_ws);
    k_conv<<<512, 256, 0, stream>>>(d_ws, out);
}